// Round 1
// baseline (890.194 us; speedup 1.0000x reference)
//
#include <hip/hip_runtime.h>
#include <math.h>

#define BATCH 131072

// ---------------------------------------------------------------------------
// Fused GEMM (+ optional input affine/lrelu) (+ optional BN stats accumulate)
// C[r, n] = sum_k f(A[r,k]) * W[k,n] + bias[n],  f = lrelu(a*sc+sh) or identity
// Tile: MT rows x NT cols (NT = full output width), K chunked by 32.
// Per-column sum / sum-of-squares reduced in LDS, accumulated to global doubles.
// ---------------------------------------------------------------------------
template<int MT, int NT, int NSTORE, int TM, int TN, int BLK, bool AFFINE, bool STATS>
__global__ __launch_bounds__(BLK)
void gemm_bn(const float* __restrict__ Ain, int K,
             const float* __restrict__ W, const float* __restrict__ bias,
             const float* __restrict__ sc, const float* __restrict__ sh,
             float* __restrict__ Xout,
             double* __restrict__ gsum, double* __restrict__ gsq)
{
    constexpr int KS  = 32;
    constexpr int MP  = MT + 4;
    constexpr int NP  = NT + 4;
    constexpr int NCG = NT / TN;   // col groups
    constexpr int RG  = MT / TM;   // row groups
    static_assert(BLK == NCG * RG, "thread mapping");

    __shared__ float As[KS][MP];   // A staged transposed: As[k][row]
    __shared__ float Bs[KS][NP];   // W staged: Bs[k][n]

    const int tid = threadIdx.x;
    const int r0  = blockIdx.x * MT;
    const int tx  = tid % NCG;
    const int ty  = tid / NCG;

    float acc[TM][TN] = {};

    const int KC = (K + KS - 1) / KS;
    for (int kc = 0; kc < KC; ++kc) {
        const int kbase = kc * KS;
        __syncthreads();
        // ---- stage A tile (apply affine + lrelu on the fly for layers 2..4)
        constexpr int AL = MT * KS / BLK;
        #pragma unroll
        for (int l = 0; l < AL; ++l) {
            int idx = tid + l * BLK;
            int i = idx >> 5;        // row within tile
            int j = idx & 31;        // k within chunk
            int gk = kbase + j;
            float v;
            if (AFFINE) {            // K is a multiple of 32 in affine layers
                v = Ain[(size_t)(r0 + i) * K + gk];
                v = v * sc[gk] + sh[gk];
                v = v > 0.f ? v : 0.2f * v;
            } else {
                v = (gk < K) ? Ain[(size_t)(r0 + i) * K + gk] : 0.f;
            }
            As[j][i] = v;
        }
        // ---- stage B tile (W row stride = NSTORE, zero-pad cols >= NSTORE)
        constexpr int BL = NT * KS / BLK;
        #pragma unroll
        for (int l = 0; l < BL; ++l) {
            int idx = tid + l * BLK;
            int kk = idx / NT;
            int n  = idx % NT;
            int gk = kbase + kk;
            float v = 0.f;
            if (gk < K && n < NSTORE) v = W[(size_t)gk * NSTORE + n];
            Bs[kk][n] = v;
        }
        __syncthreads();
        // ---- inner product: register outer-product tile
        #pragma unroll 4
        for (int k = 0; k < KS; ++k) {
            float a[TM], b[TN];
            #pragma unroll
            for (int i4 = 0; i4 < TM; i4 += 4)
                *reinterpret_cast<float4*>(&a[i4]) =
                    *reinterpret_cast<const float4*>(&As[k][ty * TM + i4]);
            #pragma unroll
            for (int j4 = 0; j4 < TN; j4 += 4)
                *reinterpret_cast<float4*>(&b[j4]) =
                    *reinterpret_cast<const float4*>(&Bs[k][tx * TN + j4]);
            #pragma unroll
            for (int i = 0; i < TM; ++i)
                #pragma unroll
                for (int j = 0; j < TN; ++j)
                    acc[i][j] = fmaf(a[i], b[j], acc[i][j]);
        }
    }

    // ---- bias, store, per-thread column partials
    float bc[TN];
    #pragma unroll
    for (int j = 0; j < TN; ++j) {
        int gc = tx * TN + j;
        bc[j] = (gc < NSTORE) ? bias[gc] : 0.f;
    }
    float psum[TN] = {};
    float psq[TN]  = {};
    #pragma unroll
    for (int i = 0; i < TM; ++i) {
        int row = r0 + ty * TM + i;
        float x[TN];
        #pragma unroll
        for (int j = 0; j < TN; ++j) {
            x[j] = acc[i][j] + bc[j];
            psum[j] += x[j];
            psq[j]  += x[j] * x[j];
        }
        if (NSTORE == NT) {
            #pragma unroll
            for (int j4 = 0; j4 < TN; j4 += 4) {
                float4 v = make_float4(x[j4], x[j4+1], x[j4+2], x[j4+3]);
                *reinterpret_cast<float4*>(&Xout[(size_t)row * NSTORE + tx * TN + j4]) = v;
            }
        } else {
            #pragma unroll
            for (int j = 0; j < TN; ++j) {
                int gc = tx * TN + j;
                if (gc < NSTORE) Xout[(size_t)row * NSTORE + gc] = x[j];
            }
        }
    }

    // ---- BN stats: LDS reduce (reuse Bs: 2*RG*NP == KS*NP exactly for RG=16)
    if (STATS) {
        __syncthreads();
        float* S1 = &Bs[0][0];
        float* S2 = S1 + RG * NP;
        #pragma unroll
        for (int j = 0; j < TN; ++j) {
            S1[ty * NP + tx * TN + j] = psum[j];
            S2[ty * NP + tx * TN + j] = psq[j];
        }
        __syncthreads();
        if (tid < NT) {
            double s = 0.0, q = 0.0;
            #pragma unroll 4
            for (int t = 0; t < RG; ++t) {
                s += (double)S1[t * NP + tid];
                q += (double)S2[t * NP + tid];
            }
            atomicAdd(&gsum[tid], s);
            atomicAdd(&gsq[tid], q);
        }
    }
}

// mu/var -> scale/shift in double:  y = x*scale + shift  ==  (x-mu)*rsqrt(var+eps)*g + be
__global__ void finalize_bn(const double* __restrict__ sum, const double* __restrict__ sq,
                            const float* __restrict__ g, const float* __restrict__ be,
                            float* __restrict__ sc, float* __restrict__ sh, int N)
{
    int i = threadIdx.x;
    if (i < N) {
        const double inv = 1.0 / (double)BATCH;
        double mu  = sum[i] * inv;
        double var = sq[i] * inv - mu * mu;
        double s   = (double)g[i] / sqrt(var + 1e-5);
        sc[i] = (float)s;
        sh[i] = (float)((double)be[i] - mu * s);
    }
}

// ---------------------------------------------------------------------------
// Gumbel top-K scan: 256 rows/block, one thread per row.
// argmax(softmax((masked+noise)/T)) == argmax over unmasked of (logit + noise)
// noise = -log(-log(u)); strict > keeps first index (jnp.argmax tie-break).
// ---------------------------------------------------------------------------
__global__ __launch_bounds__(256)
void gumbel_topk(const float* __restrict__ logits, const float* __restrict__ u,
                 float* __restrict__ out)
{
    __shared__ float lg[256 * 25];
    __shared__ float us[256 * 25];
    const int tid = threadIdx.x;
    const int r0  = blockIdx.x * 256;

    for (int idx = tid; idx < 256 * 25; idx += 256)
        lg[idx] = logits[(size_t)r0 * 25 + idx];
    __syncthreads();

    float myl[25];
    #pragma unroll
    for (int j = 0; j < 25; ++j) myl[j] = lg[tid * 25 + j];

    unsigned mask = 0x1FFFFFFu;  // 25 ones
    for (int it = 0; it < 15; ++it) {
        __syncthreads();   // protect us[] reuse
        const float* uk = u + ((size_t)it * BATCH + r0) * 25;
        for (int idx = tid; idx < 256 * 25; idx += 256)
            us[idx] = uk[idx];
        __syncthreads();

        float best = -INFINITY;
        int bj = 0;
        #pragma unroll
        for (int j = 0; j < 25; ++j) {
            float uu = us[tid * 25 + j];
            float nz = -logf(-logf(uu));       // accurate logf: argmax must match np fp32
            float v  = myl[j] + nz;
            v = ((mask >> j) & 1u) ? v : -INFINITY;
            if (v > best) { best = v; bj = j; }
        }
        mask &= ~(1u << bj);
        out[(size_t)(r0 + tid) * 15 + it] = (float)bj / 24.0f;
    }
}

extern "C" void kernel_launch(void* const* d_in, const int* in_sizes, int n_in,
                              void* d_out, int out_size, void* d_ws, size_t ws_size,
                              hipStream_t stream)
{
    (void)in_sizes; (void)n_in; (void)out_size; (void)ws_size;
    const float* z   = (const float*)d_in[0];
    const float* u   = (const float*)d_in[1];
    const float* W1  = (const float*)d_in[2];
    const float* b1  = (const float*)d_in[3];
    const float* g1  = (const float*)d_in[4];
    const float* be1 = (const float*)d_in[5];
    const float* W2  = (const float*)d_in[6];
    const float* b2  = (const float*)d_in[7];
    const float* g2  = (const float*)d_in[8];
    const float* be2 = (const float*)d_in[9];
    const float* W3  = (const float*)d_in[10];
    const float* b3  = (const float*)d_in[11];
    const float* g3  = (const float*)d_in[12];
    const float* be3 = (const float*)d_in[13];
    const float* W4  = (const float*)d_in[14];
    const float* b4  = (const float*)d_in[15];
    float* out = (float*)d_out;

    char* ws = (char*)d_ws;
    float* X2     = (float*)ws;                                  // B*256 f32 (reused as logits B*25 later)
    float* XA     = (float*)(ws + (size_t)134217728);            // B*128 f32 (X1, then X3)
    char*  statb  = ws + (size_t)134217728 + (size_t)67108864;
    double* sum1 = (double*)statb;      double* sq1 = sum1 + 128;
    double* sum2 = sq1 + 128;           double* sq2 = sum2 + 256;
    double* sum3 = sq2 + 256;           double* sq3 = sum3 + 128;
    float* sc1 = (float*)(sq3 + 128);   float* sh1 = sc1 + 128;
    float* sc2 = sh1 + 128;             float* sh2 = sc2 + 256;
    float* sc3 = sh2 + 256;             float* sh3 = sc3 + 128;
    float* logits = X2;                 // X2 region dead after P3

    // zero the double stat accumulators (1024 doubles)
    hipMemsetAsync(statb, 0, 1024 * sizeof(double), stream);

    // P1: z[B,50] @ W1[50,128] -> X1 (XA) + stats1
    gemm_bn<128,128,128, 8,8, 256, false, true>
        <<<BATCH/128, 256, 0, stream>>>(z, 50, W1, b1, nullptr, nullptr, XA, sum1, sq1);
    finalize_bn<<<1, 256, 0, stream>>>(sum1, sq1, g1, be1, sc1, sh1, 128);

    // P2: lrelu(bn(X1)) @ W2[128,256] -> X2 + stats2
    gemm_bn<128,256,256, 8,8, 512, true, true>
        <<<BATCH/128, 512, 0, stream>>>(XA, 128, W2, b2, sc1, sh1, X2, sum2, sq2);
    finalize_bn<<<1, 256, 0, stream>>>(sum2, sq2, g2, be2, sc2, sh2, 256);

    // P3: lrelu(bn(X2)) @ W3[256,128] -> X3 (XA, X1 dead) + stats3
    gemm_bn<128,128,128, 8,8, 256, true, true>
        <<<BATCH/128, 256, 0, stream>>>(X2, 256, W3, b3, sc2, sh2, XA, sum3, sq3);
    finalize_bn<<<1, 256, 0, stream>>>(sum3, sq3, g3, be3, sc3, sh3, 128);

    // P3b: lrelu(bn(X3)) @ W4[128,25] -> logits (X2 region, X2 dead)
    gemm_bn<256,32,25, 8,4, 256, true, false>
        <<<BATCH/256, 256, 0, stream>>>(XA, 128, W4, b4, sc3, sh3, logits, nullptr, nullptr);

    // P4: gumbel top-15 scan
    gumbel_topk<<<BATCH/256, 256, 0, stream>>>(logits, u, out);
}

// Round 2
// 871.076 us; speedup vs baseline: 1.0219x; 1.0219x over previous
//
#include <hip/hip_runtime.h>
#include <math.h>

#define BATCH 131072

// ---------------------------------------------------------------------------
// Fused GEMM (+ optional input affine/lrelu) (+ optional BN stats accumulate)
// C[r, n] = sum_k f(A[r,k]) * W[k,n] + bias[n],  f = lrelu(a*sc+sh) or identity
//
// Thread (ty,tx) owns TM rows x TN cols. TN is split into TN/4 float4 groups;
// group h covers columns  h*(NCG*4) + tx*4 .. +3  -> lanes read CONTIGUOUS
// 16B chunks from Bs (conflict-free), A-frag reads are broadcast across the
// NCG lanes sharing ty (<=2-way, free).
// ---------------------------------------------------------------------------
template<int MT, int NT, int NSTORE, int TM, int TN, int BLK, bool AFFINE, bool STATS>
__global__ __launch_bounds__(BLK, 2)
void gemm_bn(const float* __restrict__ Ain, int K,
             const float* __restrict__ W, const float* __restrict__ bias,
             const float* __restrict__ sc, const float* __restrict__ sh,
             float* __restrict__ Xout,
             double* __restrict__ gsum, double* __restrict__ gsq)
{
    constexpr int KS  = 32;
    constexpr int MP  = MT + 4;
    constexpr int NP  = NT + 4;
    constexpr int NCG = NT / TN;   // col groups
    constexpr int RG  = MT / TM;   // row groups
    constexpr int NH  = TN / 4;    // float4 groups per thread
    static_assert(BLK == NCG * RG, "thread mapping");
    static_assert(!STATS || 2 * RG * NP <= KS * NP, "stats reuse of Bs");

    __shared__ float As[KS][MP];   // A staged transposed: As[k][row]
    __shared__ float Bs[KS][NP];   // W staged: Bs[k][n]

    const int tid = threadIdx.x;
    const int r0  = blockIdx.x * MT;
    const int tx  = tid % NCG;
    const int ty  = tid / NCG;

    float acc[TM][TN] = {};

    const int KC = (K + KS - 1) / KS;
    for (int kc = 0; kc < KC; ++kc) {
        const int kbase = kc * KS;
        __syncthreads();
        // ---- stage A tile (apply affine + lrelu on the fly for layers 2..4)
        constexpr int AL = MT * KS / BLK;
        #pragma unroll
        for (int l = 0; l < AL; ++l) {
            int idx = tid + l * BLK;
            int i = idx >> 5;        // row within tile
            int j = idx & 31;        // k within chunk
            int gk = kbase + j;
            float v;
            if (AFFINE) {            // K is a multiple of 32 in affine layers
                v = Ain[(size_t)(r0 + i) * K + gk];
                v = v * sc[gk] + sh[gk];
                v = v > 0.f ? v : 0.2f * v;
            } else {
                v = (gk < K) ? Ain[(size_t)(r0 + i) * K + gk] : 0.f;
            }
            As[j][i] = v;
        }
        // ---- stage B tile (W row stride = NSTORE, zero-pad cols >= NSTORE)
        constexpr int BL = NT * KS / BLK;
        #pragma unroll
        for (int l = 0; l < BL; ++l) {
            int idx = tid + l * BLK;
            int kk = idx / NT;
            int n  = idx % NT;
            int gk = kbase + kk;
            float v = 0.f;
            if (gk < K && n < NSTORE) v = W[(size_t)gk * NSTORE + n];
            Bs[kk][n] = v;
        }
        __syncthreads();
        // ---- inner product: register outer-product tile
        #pragma unroll 2
        for (int k = 0; k < KS; ++k) {
            float a[TM], b[TN];
            #pragma unroll
            for (int i4 = 0; i4 < TM; i4 += 4)
                *reinterpret_cast<float4*>(&a[i4]) =
                    *reinterpret_cast<const float4*>(&As[k][ty * TM + i4]);
            #pragma unroll
            for (int h = 0; h < NH; ++h)
                *reinterpret_cast<float4*>(&b[h * 4]) =
                    *reinterpret_cast<const float4*>(&Bs[k][h * (NCG * 4) + tx * 4]);
            #pragma unroll
            for (int i = 0; i < TM; ++i)
                #pragma unroll
                for (int j = 0; j < TN; ++j)
                    acc[i][j] = fmaf(a[i], b[j], acc[i][j]);
        }
    }

    // column of register slot j:  col(j) = (j>>2)*(NCG*4) + tx*4 + (j&3)
    float bc[TN];
    #pragma unroll
    for (int j = 0; j < TN; ++j) {
        int gc = (j >> 2) * (NCG * 4) + tx * 4 + (j & 3);
        bc[j] = (gc < NSTORE) ? bias[gc] : 0.f;
    }
    float psum[TN] = {};
    float psq[TN]  = {};
    #pragma unroll
    for (int i = 0; i < TM; ++i) {
        int row = r0 + ty * TM + i;
        float x[TN];
        #pragma unroll
        for (int j = 0; j < TN; ++j) {
            x[j] = acc[i][j] + bc[j];
            psum[j] += x[j];
            psq[j]  += x[j] * x[j];
        }
        if (NSTORE == NT) {
            #pragma unroll
            for (int h = 0; h < NH; ++h) {
                float4 v = make_float4(x[h*4], x[h*4+1], x[h*4+2], x[h*4+3]);
                *reinterpret_cast<float4*>(
                    &Xout[(size_t)row * NSTORE + h * (NCG * 4) + tx * 4]) = v;
            }
        } else {
            #pragma unroll
            for (int j = 0; j < TN; ++j) {
                int gc = (j >> 2) * (NCG * 4) + tx * 4 + (j & 3);
                if (gc < NSTORE) Xout[(size_t)row * NSTORE + gc] = x[j];
            }
        }
    }

    // ---- BN stats: LDS reduce (reuse Bs; 2*RG*NP <= KS*NP)
    if (STATS) {
        __syncthreads();
        float* S1 = &Bs[0][0];
        float* S2 = S1 + RG * NP;
        #pragma unroll
        for (int j = 0; j < TN; ++j) {
            int gc = (j >> 2) * (NCG * 4) + tx * 4 + (j & 3);
            S1[ty * NP + gc] = psum[j];
            S2[ty * NP + gc] = psq[j];
        }
        __syncthreads();
        if (tid < NT) {
            double s = 0.0, q = 0.0;
            #pragma unroll 4
            for (int t = 0; t < RG; ++t) {
                s += (double)S1[t * NP + tid];
                q += (double)S2[t * NP + tid];
            }
            atomicAdd(&gsum[tid], s);
            atomicAdd(&gsq[tid], q);
        }
    }
}

// mu/var -> scale/shift in double:  y = x*scale + shift  ==  (x-mu)*rsqrt(var+eps)*g + be
__global__ void finalize_bn(const double* __restrict__ sum, const double* __restrict__ sq,
                            const float* __restrict__ g, const float* __restrict__ be,
                            float* __restrict__ sc, float* __restrict__ sh, int N)
{
    int i = threadIdx.x;
    if (i < N) {
        const double inv = 1.0 / (double)BATCH;
        double mu  = sum[i] * inv;
        double var = sq[i] * inv - mu * mu;
        double s   = (double)g[i] / sqrt(var + 1e-5);
        sc[i] = (float)s;
        sh[i] = (float)((double)be[i] - mu * s);
    }
}

// ---------------------------------------------------------------------------
// Gumbel top-K scan: 256 rows/block, one thread per row.
// argmax(softmax((masked+noise)/T)) == argmax over unmasked of (logit + noise)
// noise = -log(-log(u)); strict > keeps first index (jnp.argmax tie-break).
// ---------------------------------------------------------------------------
__global__ __launch_bounds__(256)
void gumbel_topk(const float* __restrict__ logits, const float* __restrict__ u,
                 float* __restrict__ out)
{
    __shared__ float lg[256 * 25];
    __shared__ float us[256 * 25];
    const int tid = threadIdx.x;
    const int r0  = blockIdx.x * 256;

    for (int idx = tid; idx < 256 * 25; idx += 256)
        lg[idx] = logits[(size_t)r0 * 25 + idx];
    __syncthreads();

    float myl[25];
    #pragma unroll
    for (int j = 0; j < 25; ++j) myl[j] = lg[tid * 25 + j];

    unsigned mask = 0x1FFFFFFu;  // 25 ones
    for (int it = 0; it < 15; ++it) {
        __syncthreads();   // protect us[] reuse
        const float* uk = u + ((size_t)it * BATCH + r0) * 25;
        for (int idx = tid; idx < 256 * 25; idx += 256)
            us[idx] = uk[idx];
        __syncthreads();

        float best = -INFINITY;
        int bj = 0;
        #pragma unroll
        for (int j = 0; j < 25; ++j) {
            float uu = us[tid * 25 + j];
            float nz = -logf(-logf(uu));       // accurate logf: argmax must match np fp32
            float v  = myl[j] + nz;
            v = ((mask >> j) & 1u) ? v : -INFINITY;
            if (v > best) { best = v; bj = j; }
        }
        mask &= ~(1u << bj);
        out[(size_t)(r0 + tid) * 15 + it] = (float)bj / 24.0f;
    }
}

extern "C" void kernel_launch(void* const* d_in, const int* in_sizes, int n_in,
                              void* d_out, int out_size, void* d_ws, size_t ws_size,
                              hipStream_t stream)
{
    (void)in_sizes; (void)n_in; (void)out_size; (void)ws_size;
    const float* z   = (const float*)d_in[0];
    const float* u   = (const float*)d_in[1];
    const float* W1  = (const float*)d_in[2];
    const float* b1  = (const float*)d_in[3];
    const float* g1  = (const float*)d_in[4];
    const float* be1 = (const float*)d_in[5];
    const float* W2  = (const float*)d_in[6];
    const float* b2  = (const float*)d_in[7];
    const float* g2  = (const float*)d_in[8];
    const float* be2 = (const float*)d_in[9];
    const float* W3  = (const float*)d_in[10];
    const float* b3  = (const float*)d_in[11];
    const float* g3  = (const float*)d_in[12];
    const float* be3 = (const float*)d_in[13];
    const float* W4  = (const float*)d_in[14];
    const float* b4  = (const float*)d_in[15];
    float* out = (float*)d_out;

    char* ws = (char*)d_ws;
    float* X2     = (float*)ws;                                  // B*256 f32 (reused as logits B*25 later)
    float* XA     = (float*)(ws + (size_t)134217728);            // B*128 f32 (X1, then X3)
    char*  statb  = ws + (size_t)134217728 + (size_t)67108864;
    double* sum1 = (double*)statb;      double* sq1 = sum1 + 128;
    double* sum2 = sq1 + 128;           double* sq2 = sum2 + 256;
    double* sum3 = sq2 + 256;           double* sq3 = sum3 + 128;
    float* sc1 = (float*)(sq3 + 128);   float* sh1 = sc1 + 128;
    float* sc2 = sh1 + 128;             float* sh2 = sc2 + 256;
    float* sc3 = sh2 + 256;             float* sh3 = sc3 + 128;
    float* logits = X2;                 // X2 region dead after P3

    // zero the double stat accumulators (1024 doubles)
    hipMemsetAsync(statb, 0, 1024 * sizeof(double), stream);

    // P1: z[B,50] @ W1[50,128] -> X1 (XA) + stats1
    gemm_bn<256,128,128, 16,8, 256, false, true>
        <<<BATCH/256, 256, 0, stream>>>(z, 50, W1, b1, nullptr, nullptr, XA, sum1, sq1);
    finalize_bn<<<1, 256, 0, stream>>>(sum1, sq1, g1, be1, sc1, sh1, 128);

    // P2: lrelu(bn(X1)) @ W2[128,256] -> X2 + stats2
    gemm_bn<128,256,256, 16,8, 256, true, true>
        <<<BATCH/128, 256, 0, stream>>>(XA, 128, W2, b2, sc1, sh1, X2, sum2, sq2);
    finalize_bn<<<1, 256, 0, stream>>>(sum2, sq2, g2, be2, sc2, sh2, 256);

    // P3: lrelu(bn(X2)) @ W3[256,128] -> X3 (XA, X1 dead) + stats3
    gemm_bn<256,128,128, 16,8, 256, true, true>
        <<<BATCH/256, 256, 0, stream>>>(X2, 256, W3, b3, sc2, sh2, XA, sum3, sq3);
    finalize_bn<<<1, 256, 0, stream>>>(sum3, sq3, g3, be3, sc3, sh3, 128);

    // P3b: lrelu(bn(X3)) @ W4[128,25] -> logits (X2 region, X2 dead)
    gemm_bn<256,32,25, 8,4, 256, true, false>
        <<<BATCH/256, 256, 0, stream>>>(XA, 128, W4, b4, sc3, sh3, logits, nullptr, nullptr);

    // P4: gumbel top-15 scan
    gumbel_topk<<<BATCH/256, 256, 0, stream>>>(logits, u, out);
}